// Round 4
// baseline (279.985 us; speedup 1.0000x reference)
//
#include <hip/hip_runtime.h>

typedef __attribute__((ext_vector_type(8))) short bf16x8;
typedef __attribute__((ext_vector_type(4))) float f32x4;
typedef __attribute__((ext_vector_type(16))) float f32x16;

static __device__ __forceinline__ unsigned short f2bf(float f) {
    union { float f; unsigned int u; } v; v.f = f;
    unsigned int r = v.u + 0x7FFFu + ((v.u >> 16) & 1u);
    return (unsigned short)(r >> 16);
}

static __device__ __forceinline__ unsigned cvtpk_bf16(float lo, float hi) {
    unsigned r;
    asm("v_cvt_pk_bf16_f32 %0, %1, %2" : "=v"(r) : "v"(lo), "v"(hi));
    return r;
}

#define NRW (27 * 16384)

// Repack Wq/Wk/Wv -> RW[conv][kh][kw][cc][g][o][8s] bf16 (B-frag-ready), Wo -> bf16 [o][c]
__global__ __launch_bounds__(256) void repack_k(const float* __restrict__ Wq, const float* __restrict__ Wk,
                                                const float* __restrict__ Wv, const float* __restrict__ Wo,
                                                unsigned short* __restrict__ RW, unsigned short* __restrict__ WoB) {
    int t = blockIdx.x * 256 + threadIdx.x;
    if (t < NRW) {
        int s = t & 7, o = (t >> 3) & 127, g = (t >> 10) & 3, cc = (t >> 12) & 3, tap = t >> 14;
        int conv = tap / 9, kk = tap % 9, kh = kk / 3, kw = kk % 3;
        int c = cc * 32 + g * 8 + s;
        const float* W = (conv == 0) ? Wq : ((conv == 1) ? Wk : Wv);
        RW[t] = f2bf(W[((o * 128 + c) * 3 + kh) * 3 + kw]);
    } else {
        int u = t - NRW;
        if (u < 16384) WoB[u] = f2bf(Wo[u]);
    }
}

// Fused QKV 3x3 conv, implicit GEMM. Block = (b, h): M=64 (w), N=384 (3 convs x 128 o), K=1152.
__global__ __launch_bounds__(256) void qkv_conv_k(const float* __restrict__ x, const unsigned short* __restrict__ RW,
                                                  const float* __restrict__ bq, const float* __restrict__ bk,
                                                  const float* __restrict__ bv,
                                                  unsigned short* __restrict__ q_ws, unsigned short* __restrict__ k_ws,
                                                  unsigned short* __restrict__ v_ws) {
    __shared__ unsigned short xs[3 * 66 * 128];  // [kh][w+1 (66 padded)][c], swizzled ^((row&7)<<4)
    const int tid = threadIdx.x;
    const int b = blockIdx.x >> 6, h = blockIdx.x & 63;
    for (int i = tid; i < 3 * 66 * 128; i += 256) xs[i] = 0;
    __syncthreads();
    for (int ch = tid; ch < 3 * 128 * 16; ch += 256) {
        int r3 = ch >> 11, rem = ch & 2047, c = rem >> 4, w4 = rem & 15;
        int hh = h - 1 + r3;
        if (hh >= 0 && hh < 64) {
            float4 v = *(const float4*)(x + ((b * 128 + c) * 64 + hh) * 64 + w4 * 4);
            float vv[4] = {v.x, v.y, v.z, v.w};
#pragma unroll
            for (int j = 0; j < 4; ++j) {
                int wr = w4 * 4 + j + 1;
                unsigned int byte = (unsigned int)(((r3 * 66 + wr) * 128 + c) * 2) ^ ((wr & 7) << 4);
                *(unsigned short*)((char*)xs + byte) = f2bf(vv[j]);
            }
        }
    }
    __syncthreads();
    const int lane = tid & 63, wave = tid >> 6;
    const int l15 = lane & 15, g = lane >> 4;
    f32x4 acc[4][6];
#pragma unroll
    for (int i = 0; i < 4; ++i)
#pragma unroll
        for (int j = 0; j < 6; ++j) acc[i][j] = (f32x4){0.f, 0.f, 0.f, 0.f};
#pragma unroll 1
    for (int kk = 0; kk < 9; ++kk) {
        const int kw = kk % 3;
#pragma unroll 2
        for (int cc = 0; cc < 4; ++cc) {
            bf16x8 a[4];
#pragma unroll
            for (int mf = 0; mf < 4; ++mf) {
                int wr = mf * 16 + l15 + kw;
                unsigned int byte = (unsigned int)((((kk / 3) * 66 + wr) * 128 + cc * 32 + g * 8) * 2) ^ ((wr & 7) << 4);
                a[mf] = *(const bf16x8*)((const char*)xs + byte);
            }
#pragma unroll
            for (int n6 = 0; n6 < 6; ++n6) {
                int nt = wave * 6 + n6;
                int conv = nt >> 3;
                int o = (nt * 16 + l15) & 127;
                bf16x8 bfr = *(const bf16x8*)(RW + ((((conv * 9 + kk) * 4 + cc) * 4 + g) * 128 + o) * 8);
#pragma unroll
                for (int mf = 0; mf < 4; ++mf)
                    acc[mf][n6] = __builtin_amdgcn_mfma_f32_16x16x32_bf16(a[mf], bfr, acc[mf][n6], 0, 0, 0);
            }
        }
    }
    const float SCALE = 0.08838834764831845f;  // 1/sqrt(128), folded into q
#pragma unroll
    for (int n6 = 0; n6 < 6; ++n6) {
        int nt = wave * 6 + n6;
        int conv = nt >> 3;
        int o = (nt * 16 + l15) & 127;
        float bias = (conv == 0) ? bq[o] : ((conv == 1) ? bk[o] : bv[o]);
#pragma unroll
        for (int mf = 0; mf < 4; ++mf) {
#pragma unroll
            for (int r = 0; r < 4; ++r) {
                int pos = h * 64 + mf * 16 + g * 4 + r;
                float val = acc[mf][n6][r] + bias;
                if (conv == 0)      q_ws[(b * 4096 + pos) * 128 + o] = f2bf(val * SCALE);
                else if (conv == 1) k_ws[(b * 4096 + pos) * 128 + o] = f2bf(val);
                else                v_ws[(b * 128 + o) * 4096 + pos] = f2bf(val);
            }
        }
    }
}

#define AS1C(p) ((const __attribute__((address_space(1))) void*)(p))
#define AS3(p)  ((__attribute__((address_space(3))) void*)(p))

// Flash attention (4-way split-KV) + fused 1x1 conv + bias + residual.
// Block = (b, 128-row q tile), 8 waves = 2 wi (64 i, 2 iq blocks) x 4 wj (32 j each).
// Each K/V A-frag read feeds 2 MFMAs (iq=0,1) -> half the LDS reads per MAC vs r3.
// KV tile = 128 j double-buffered; P exchange fully in-register via permlane32_swap.
__global__ __launch_bounds__(512, 2) void attn_k(
    const unsigned short* __restrict__ q_ws, const unsigned short* __restrict__ k_ws,
    const unsigned short* __restrict__ v_ws, const unsigned short* __restrict__ WoB,
    const float* __restrict__ bo, const float* __restrict__ x, float* __restrict__ out) {
    __shared__ __align__(16) char smem[135168];

    const int tid = threadIdx.x;
    const int lane = tid & 63, wave = tid >> 6;
    const int wj = wave & 3, wi = wave >> 2;
    const int l31 = lane & 31, h = lane >> 5;
    const int b = blockIdx.x & 7;              // batch -> XCD affinity
    const int ibase = (blockIdx.x >> 3) * 128;

    // global_load_lds staging: linear LDS dest, pre-swizzled global source (chunk ^ row&15).
    const char* kg[4]; const char* vg[4]; int ldsoff[4];
#pragma unroll
    for (int q = 0; q < 4; ++q) {
        int slot = (wave * 4 + q) * 64 + lane;   // 16B slot index 0..2047
        int row = slot >> 4, s = slot & 15;
        int cs = s ^ (row & 15);
        kg[q] = (const char*)(k_ws + ((size_t)b * 4096 + row) * 128 + cs * 8);  // row=j, chunk=c
        vg[q] = (const char*)(v_ws + ((size_t)b * 128 + row) * 4096 + cs * 8);  // row=c, chunk=j
        ldsoff[q] = (wave * 4 + q) * 1024;
    }
    // prologue: stage tile 0 into buffer 0
#pragma unroll
    for (int q = 0; q < 4; ++q)
        __builtin_amdgcn_global_load_lds(AS1C(kg[q]), AS3(smem + ldsoff[q]), 16, 0, 0);
#pragma unroll
    for (int q = 0; q < 4; ++q)
        __builtin_amdgcn_global_load_lds(AS1C(vg[q]), AS3(smem + 32768 + ldsoff[q]), 16, 0, 0);

    // Q fragments: B-operand, col=i (2 iq blocks), k=c
    bf16x8 qf[2][8];
#pragma unroll
    for (int iq = 0; iq < 2; ++iq) {
        const unsigned short* qrow = q_ws + ((size_t)b * 4096 + ibase + wi * 64 + iq * 32 + l31) * 128;
#pragma unroll
        for (int cc = 0; cc < 8; ++cc) qf[iq][cc] = *(const bf16x8*)(qrow + cc * 16 + h * 8);
    }

    f32x16 oac[4][2];
#pragma unroll
    for (int cf = 0; cf < 4; ++cf)
#pragma unroll
        for (int iq = 0; iq < 2; ++iq)
#pragma unroll
            for (int r = 0; r < 16; ++r) oac[cf][iq][r] = 0.f;
    float m[2] = {-1e30f, -1e30f}, ssum[2] = {0.f, 0.f};

    __syncthreads();  // tile 0 staged

#pragma unroll 1
    for (int kt = 0; kt < 32; ++kt) {
        const int cur = kt & 1;
        const char* Kc = smem + cur * 65536;
        const char* Vc = Kc + 32768;
        if (kt < 31) {  // prefetch tile kt+1 into the other buffer (drained at end barrier)
            char* Kn = smem + (cur ^ 1) * 65536;
            char* Vn = Kn + 32768;
            const size_t kb = (size_t)(kt + 1) * 32768;  // 128 j * 256 B
            const size_t vb = (size_t)(kt + 1) * 256;    // 128 j * 2 B
#pragma unroll
            for (int q = 0; q < 4; ++q)
                __builtin_amdgcn_global_load_lds(AS1C(kg[q] + kb), AS3(Kn + ldsoff[q]), 16, 0, 0);
#pragma unroll
            for (int q = 0; q < 4; ++q)
                __builtin_amdgcn_global_load_lds(AS1C(vg[q] + vb), AS3(Vn + ldsoff[q]), 16, 0, 0);
        }

        // S^T[j][i] = K·Q^T over this wave's 32-j slice, both iq blocks
        f32x16 st[2];
#pragma unroll
        for (int iq = 0; iq < 2; ++iq)
#pragma unroll
            for (int r = 0; r < 16; ++r) st[iq][r] = 0.f;
        const int jrow = wj * 32 + l31;
#pragma unroll
        for (int cc = 0; cc < 8; ++cc) {
            unsigned byte = (unsigned)(jrow * 256 + cc * 32 + h * 16) ^ ((jrow & 15) << 4);
            bf16x8 kf = *(const bf16x8*)(Kc + byte);
            st[0] = __builtin_amdgcn_mfma_f32_32x32x16_bf16(kf, qf[0][cc], st[0], 0, 0, 0);
            st[1] = __builtin_amdgcn_mfma_f32_32x32x16_bf16(kf, qf[1][cc], st[1], 0, 0, 0);
        }

        // online softmax per iq over this slice's 32 j (16 in-lane + 1 xor32 shuffle)
        float tm[2];
#pragma unroll
        for (int iq = 0; iq < 2; ++iq) {
            float tmax = st[iq][0];
#pragma unroll
            for (int r = 1; r < 16; ++r) tmax = fmaxf(tmax, st[iq][r]);
            tmax = fmaxf(tmax, __shfl_xor(tmax, 32));
            tm[iq] = tmax;
        }
        if (!__all(tm[0] <= m[0] && tm[1] <= m[1])) {  // defer-rescale
#pragma unroll
            for (int iq = 0; iq < 2; ++iq) {
                float mnew = fmaxf(m[iq], tm[iq]);
                float corr = __expf(m[iq] - mnew);
                ssum[iq] *= corr;
#pragma unroll
                for (int cf = 0; cf < 4; ++cf)
#pragma unroll
                    for (int r = 0; r < 16; ++r) oac[cf][iq][r] *= corr;
                m[iq] = mnew;
            }
        }
        // pack P to bf16 pairs: u[iq][gq][w] covers j = 8gq + 4h + (2w..2w+1)
        unsigned u[2][4][2];
#pragma unroll
        for (int iq = 0; iq < 2; ++iq) {
            float psum = 0.f;
#pragma unroll
            for (int gq = 0; gq < 4; ++gq) {
                float p0 = __expf(st[iq][gq * 4 + 0] - m[iq]);
                float p1 = __expf(st[iq][gq * 4 + 1] - m[iq]);
                float p2 = __expf(st[iq][gq * 4 + 2] - m[iq]);
                float p3 = __expf(st[iq][gq * 4 + 3] - m[iq]);
                psum += (p0 + p1) + (p2 + p3);
                u[iq][gq][0] = cvtpk_bf16(p0, p1);
                u[iq][gq][1] = cvtpk_bf16(p2, p3);
            }
            psum += __shfl_xor(psum, 32);
            ssum[iq] += psum;
        }

        // in-register cross-h exchange via permlane32_swap -> PV B-frags pa[js][iq]
        // swap(a,b): a' = {a.lo, b.lo} (= w0/w1), b' = {a.hi, b.hi} (= w2/w3)
        bf16x8 pa[2][2];
#pragma unroll
        for (int js = 0; js < 2; ++js)
#pragma unroll
            for (int iq = 0; iq < 2; ++iq) {
                unsigned a0 = u[iq][2 * js][0], b0 = u[iq][2 * js + 1][0];
                unsigned a1 = u[iq][2 * js][1], b1 = u[iq][2 * js + 1][1];
                auto r0 = __builtin_amdgcn_permlane32_swap(a0, b0, false, false);
                auto r1 = __builtin_amdgcn_permlane32_swap(a1, b1, false, false);
                union { unsigned w[4]; bf16x8 v; } pu;
                pu.w[0] = r0[0];
                pu.w[1] = r1[0];
                pu.w[2] = r0[1];
                pu.w[3] = r1[1];
                pa[js][iq] = pu.v;
            }

        // out2[c][i] += V (A, rows c, k=j) x P^T (B, cols i, k=j) over this slice's 32 j
#pragma unroll
        for (int js = 0; js < 2; ++js) {
            const int jcol = wj * 32 + js * 16 + h * 8;
#pragma unroll
            for (int cf = 0; cf < 4; ++cf) {
                int crow = cf * 32 + l31;
                unsigned vbyte = (unsigned)(crow * 256 + jcol * 2) ^ ((crow & 15) << 4);
                bf16x8 va = *(const bf16x8*)(Vc + vbyte);
                oac[cf][0] = __builtin_amdgcn_mfma_f32_32x32x16_bf16(va, pa[js][0], oac[cf][0], 0, 0, 0);
                oac[cf][1] = __builtin_amdgcn_mfma_f32_32x32x16_bf16(va, pa[js][1], oac[cf][1], 0, 0, 0);
            }
        }
        __syncthreads();  // prefetch drained + all reads of cur done -> next iter may restage
    }

    // ---- epilogue: 4-way split-KV combine, then fused 1x1 conv + bias + residual ----
    float* sRed = (float*)(smem + 131072);  // [4 wj][128 i][2] (m, ssum)
    if (h == 0) {
#pragma unroll
        for (int iq = 0; iq < 2; ++iq) {
            int it = wi * 64 + iq * 32 + l31;
            sRed[(wj * 128 + it) * 2] = m[iq];
            sRed[(wj * 128 + it) * 2 + 1] = ssum[iq];
        }
    }
    __syncthreads();
    float aS[2];
#pragma unroll
    for (int iq = 0; iq < 2; ++iq) {
        int it = wi * 64 + iq * 32 + l31;
        float m0 = sRed[(0 * 128 + it) * 2], s0 = sRed[(0 * 128 + it) * 2 + 1];
        float m1 = sRed[(1 * 128 + it) * 2], s1 = sRed[(1 * 128 + it) * 2 + 1];
        float m2 = sRed[(2 * 128 + it) * 2], s2 = sRed[(2 * 128 + it) * 2 + 1];
        float m3 = sRed[(3 * 128 + it) * 2], s3 = sRed[(3 * 128 + it) * 2 + 1];
        float M = fmaxf(fmaxf(m0, m1), fmaxf(m2, m3));
        float stot = __expf(m0 - M) * s0 + __expf(m1 - M) * s1 + __expf(m2 - M) * s2 + __expf(m3 - M) * s3;
        aS[iq] = __expf(m[iq] - M) / stot;
    }

    // O combine: sBig0 (wj2) / sBig1 (wj3), f32 [128 i][512B row], swz ^((i&7)<<4)
    float* sBig0 = (float*)smem;
    float* sBig1 = (float*)(smem + 65536);
    if (wj >= 2) {
        char* B = (wj == 2) ? (char*)sBig0 : (char*)sBig1;
#pragma unroll
        for (int cf = 0; cf < 4; ++cf)
#pragma unroll
            for (int iq = 0; iq < 2; ++iq)
#pragma unroll
                for (int g = 0; g < 4; ++g) {
                    int it = wi * 64 + iq * 32 + l31;
                    int c = cf * 32 + g * 8 + 4 * h;
                    f32x4 v;
#pragma unroll
                    for (int k = 0; k < 4; ++k) v[k] = oac[cf][iq][4 * g + k] * aS[iq];
                    unsigned byte = (unsigned)(it * 512 + c * 4) ^ ((it & 7) << 4);
                    *(f32x4*)(B + byte) = v;
                }
    }
    __syncthreads();
    if (wj == 0) {  // fold own (scaled) + sBig0 into oac
#pragma unroll
        for (int cf = 0; cf < 4; ++cf)
#pragma unroll
            for (int iq = 0; iq < 2; ++iq)
#pragma unroll
                for (int g = 0; g < 4; ++g) {
                    int it = wi * 64 + iq * 32 + l31;
                    int c = cf * 32 + g * 8 + 4 * h;
                    unsigned byte = (unsigned)(it * 512 + c * 4) ^ ((it & 7) << 4);
                    f32x4 rd = *(const f32x4*)((const char*)sBig0 + byte);
#pragma unroll
                    for (int k = 0; k < 4; ++k) oac[cf][iq][4 * g + k] = oac[cf][iq][4 * g + k] * aS[iq] + rd[k];
                }
    } else if (wj == 1) {  // own (scaled) + sBig1 -> write back sBig1
#pragma unroll
        for (int cf = 0; cf < 4; ++cf)
#pragma unroll
            for (int iq = 0; iq < 2; ++iq)
#pragma unroll
                for (int g = 0; g < 4; ++g) {
                    int it = wi * 64 + iq * 32 + l31;
                    int c = cf * 32 + g * 8 + 4 * h;
                    unsigned byte = (unsigned)(it * 512 + c * 4) ^ ((it & 7) << 4);
                    f32x4 rd = *(const f32x4*)((const char*)sBig1 + byte);
                    f32x4 v;
#pragma unroll
                    for (int k = 0; k < 4; ++k) v[k] = oac[cf][iq][4 * g + k] * aS[iq] + rd[k];
                    *(f32x4*)((char*)sBig1 + byte) = v;
                }
    }
    __syncthreads();
    unsigned short* sOut = (unsigned short*)smem;  // [128 i][128 c] bf16, swz ^((i&15)<<4); aliases sBig0
    if (wj == 0) {
#pragma unroll
        for (int cf = 0; cf < 4; ++cf)
#pragma unroll
            for (int iq = 0; iq < 2; ++iq)
#pragma unroll
                for (int g = 0; g < 4; ++g) {
                    int it = wi * 64 + iq * 32 + l31;
                    int c = cf * 32 + g * 8 + 4 * h;
                    unsigned rbyte = (unsigned)(it * 512 + c * 4) ^ ((it & 7) << 4);
                    f32x4 r1 = *(const f32x4*)((const char*)sBig1 + rbyte);
                    float t0 = oac[cf][iq][4 * g + 0] + r1[0];
                    float t1 = oac[cf][iq][4 * g + 1] + r1[1];
                    float t2 = oac[cf][iq][4 * g + 2] + r1[2];
                    float t3 = oac[cf][iq][4 * g + 3] + r1[3];
                    uint2 pk;
                    pk.x = cvtpk_bf16(t0, t1);
                    pk.y = cvtpk_bf16(t2, t3);
                    unsigned wbyte = (unsigned)(it * 256 + c * 2) ^ ((it & 15) << 4);
                    *(uint2*)((char*)sOut + wbyte) = pk;
                }
    }
    __syncthreads();

    // 1x1 conv: D[o][i] = Wo x out2, 16 tiles of 32x32 over 8 waves (2 each)
#pragma unroll
    for (int t = 0; t < 2; ++t) {
        int tt = wave + t * 8;
        int of = tt >> 2, ifl = tt & 3;
        int ir = ifl * 32 + l31;
        f32x16 acc;
#pragma unroll
        for (int r = 0; r < 16; ++r) acc[r] = 0.f;
#pragma unroll
        for (int cc = 0; cc < 8; ++cc) {
            unsigned bbyte = (unsigned)(ir * 256 + cc * 32 + h * 16) ^ ((ir & 15) << 4);
            bf16x8 bfr = *(const bf16x8*)((const char*)sOut + bbyte);
            bf16x8 wa = *(const bf16x8*)(WoB + (of * 32 + l31) * 128 + cc * 16 + h * 8);
            acc = __builtin_amdgcn_mfma_f32_32x32x16_bf16(wa, bfr, acc, 0, 0, 0);
        }
        int iglob = ibase + ir;
#pragma unroll
        for (int r = 0; r < 16; ++r) {
            int o = of * 32 + (r & 3) + 8 * (r >> 2) + 4 * h;
            size_t gidx = ((size_t)b * 128 + o) * 4096 + iglob;
            out[gidx] = acc[r] + bo[o] + x[gidx];
        }
    }
}

extern "C" void kernel_launch(void* const* d_in, const int* in_sizes, int n_in,
                              void* d_out, int out_size, void* d_ws, size_t ws_size,
                              hipStream_t stream) {
    const float* x  = (const float*)d_in[0];
    const float* Wq = (const float*)d_in[1];
    const float* bq = (const float*)d_in[2];
    const float* Wk = (const float*)d_in[3];
    const float* bk = (const float*)d_in[4];
    const float* Wv = (const float*)d_in[5];
    const float* bv = (const float*)d_in[6];
    const float* Wo = (const float*)d_in[7];
    const float* bo = (const float*)d_in[8];
    char* ws = (char*)d_ws;
    unsigned short* q_ws = (unsigned short*)(ws);              //  8 MB  [b][n][c] bf16 (pre-scaled)
    unsigned short* k_ws = (unsigned short*)(ws + 8388608);    //  8 MB  [b][n][c] bf16
    unsigned short* v_ws = (unsigned short*)(ws + 16777216);   //  8 MB  [b][c][n] bf16
    unsigned short* RW   = (unsigned short*)(ws + 25165824);   //  884 KB repacked qkv weights
    unsigned short* WoB  = (unsigned short*)(ws + 26050560);   //  32 KB  Wo bf16
    float* out = (float*)d_out;

    hipLaunchKernelGGL(repack_k, dim3(1792), dim3(256), 0, stream, Wq, Wk, Wv, Wo, RW, WoB);
    hipLaunchKernelGGL(qkv_conv_k, dim3(512), dim3(256), 0, stream, x, RW, bq, bk, bv, q_ws, k_ws, v_ws);
    hipLaunchKernelGGL(attn_k, dim3(256), dim3(512), 0, stream, q_ws, k_ws, v_ws, WoB, bo, x, out);
}

// Round 5
// 262.237 us; speedup vs baseline: 1.0677x; 1.0677x over previous
//
#include <hip/hip_runtime.h>

typedef __attribute__((ext_vector_type(8))) short bf16x8;
typedef __attribute__((ext_vector_type(4))) float f32x4;
typedef __attribute__((ext_vector_type(16))) float f32x16;

static __device__ __forceinline__ unsigned short f2bf(float f) {
    union { float f; unsigned int u; } v; v.f = f;
    unsigned int r = v.u + 0x7FFFu + ((v.u >> 16) & 1u);
    return (unsigned short)(r >> 16);
}

static __device__ __forceinline__ unsigned cvtpk_bf16(float lo, float hi) {
    unsigned r;
    asm("v_cvt_pk_bf16_f32 %0, %1, %2" : "=v"(r) : "v"(lo), "v"(hi));
    return r;
}

#define NRW (27 * 16384)

// Repack Wq/Wk/Wv -> RW[conv][kh][kw][cc][g][o][8s] bf16 (B-frag-ready), Wo -> bf16 [o][c]
__global__ __launch_bounds__(256) void repack_k(const float* __restrict__ Wq, const float* __restrict__ Wk,
                                                const float* __restrict__ Wv, const float* __restrict__ Wo,
                                                unsigned short* __restrict__ RW, unsigned short* __restrict__ WoB) {
    int t = blockIdx.x * 256 + threadIdx.x;
    if (t < NRW) {
        int s = t & 7, o = (t >> 3) & 127, g = (t >> 10) & 3, cc = (t >> 12) & 3, tap = t >> 14;
        int conv = tap / 9, kk = tap % 9, kh = kk / 3, kw = kk % 3;
        int c = cc * 32 + g * 8 + s;
        const float* W = (conv == 0) ? Wq : ((conv == 1) ? Wk : Wv);
        RW[t] = f2bf(W[((o * 128 + c) * 3 + kh) * 3 + kw]);
    } else {
        int u = t - NRW;
        if (u < 16384) WoB[u] = f2bf(Wo[u]);
    }
}

// Fused QKV 3x3 conv, implicit GEMM. Block = (b, h): M=64 (w), N=384 (3 convs x 128 o), K=1152.
__global__ __launch_bounds__(256) void qkv_conv_k(const float* __restrict__ x, const unsigned short* __restrict__ RW,
                                                  const float* __restrict__ bq, const float* __restrict__ bk,
                                                  const float* __restrict__ bv,
                                                  unsigned short* __restrict__ q_ws, unsigned short* __restrict__ k_ws,
                                                  unsigned short* __restrict__ v_ws) {
    __shared__ unsigned short xs[3 * 66 * 128];  // [kh][w+1 (66 padded)][c], swizzled ^((row&7)<<4)
    const int tid = threadIdx.x;
    const int b = blockIdx.x >> 6, h = blockIdx.x & 63;
    for (int i = tid; i < 3 * 66 * 128; i += 256) xs[i] = 0;
    __syncthreads();
    for (int ch = tid; ch < 3 * 128 * 16; ch += 256) {
        int r3 = ch >> 11, rem = ch & 2047, c = rem >> 4, w4 = rem & 15;
        int hh = h - 1 + r3;
        if (hh >= 0 && hh < 64) {
            float4 v = *(const float4*)(x + ((b * 128 + c) * 64 + hh) * 64 + w4 * 4);
            float vv[4] = {v.x, v.y, v.z, v.w};
#pragma unroll
            for (int j = 0; j < 4; ++j) {
                int wr = w4 * 4 + j + 1;
                unsigned int byte = (unsigned int)(((r3 * 66 + wr) * 128 + c) * 2) ^ ((wr & 7) << 4);
                *(unsigned short*)((char*)xs + byte) = f2bf(vv[j]);
            }
        }
    }
    __syncthreads();
    const int lane = tid & 63, wave = tid >> 6;
    const int l15 = lane & 15, g = lane >> 4;
    f32x4 acc[4][6];
#pragma unroll
    for (int i = 0; i < 4; ++i)
#pragma unroll
        for (int j = 0; j < 6; ++j) acc[i][j] = (f32x4){0.f, 0.f, 0.f, 0.f};
#pragma unroll 1
    for (int kk = 0; kk < 9; ++kk) {
        const int kw = kk % 3;
#pragma unroll 2
        for (int cc = 0; cc < 4; ++cc) {
            bf16x8 a[4];
#pragma unroll
            for (int mf = 0; mf < 4; ++mf) {
                int wr = mf * 16 + l15 + kw;
                unsigned int byte = (unsigned int)((((kk / 3) * 66 + wr) * 128 + cc * 32 + g * 8) * 2) ^ ((wr & 7) << 4);
                a[mf] = *(const bf16x8*)((const char*)xs + byte);
            }
#pragma unroll
            for (int n6 = 0; n6 < 6; ++n6) {
                int nt = wave * 6 + n6;
                int conv = nt >> 3;
                int o = (nt * 16 + l15) & 127;
                bf16x8 bfr = *(const bf16x8*)(RW + ((((conv * 9 + kk) * 4 + cc) * 4 + g) * 128 + o) * 8);
#pragma unroll
                for (int mf = 0; mf < 4; ++mf)
                    acc[mf][n6] = __builtin_amdgcn_mfma_f32_16x16x32_bf16(a[mf], bfr, acc[mf][n6], 0, 0, 0);
            }
        }
    }
    const float SCALE = 0.08838834764831845f;  // 1/sqrt(128), folded into q
#pragma unroll
    for (int n6 = 0; n6 < 6; ++n6) {
        int nt = wave * 6 + n6;
        int conv = nt >> 3;
        int o = (nt * 16 + l15) & 127;
        float bias = (conv == 0) ? bq[o] : ((conv == 1) ? bk[o] : bv[o]);
#pragma unroll
        for (int mf = 0; mf < 4; ++mf) {
#pragma unroll
            for (int r = 0; r < 4; ++r) {
                int pos = h * 64 + mf * 16 + g * 4 + r;
                float val = acc[mf][n6][r] + bias;
                if (conv == 0)      q_ws[(b * 4096 + pos) * 128 + o] = f2bf(val * SCALE);
                else if (conv == 1) k_ws[(b * 4096 + pos) * 128 + o] = f2bf(val);
                else                v_ws[(b * 128 + o) * 4096 + pos] = f2bf(val);
            }
        }
    }
}

#define AS1C(p) ((const __attribute__((address_space(1))) void*)(p))
#define AS3(p)  ((__attribute__((address_space(3))) void*)(p))

// Flash attention (4-way split-KV) + fused 1x1 conv + bias + residual.
// Block = (b, 128-row q tile), 8 waves = 2 wi (64 i, 2 iq blocks) x 4 wj (32 j each).
// Each K/V A-frag read feeds 2 MFMAs (iq=0,1). KV tile = 128 j, double-buffered.
// P exchange fully in-register via permlane32_swap; exp->pack fused (no u array);
// staging addresses recomputed inline (no pointer arrays) to stay under 256 VGPRs.
__global__ __launch_bounds__(512, 2) void attn_k(
    const unsigned short* __restrict__ q_ws, const unsigned short* __restrict__ k_ws,
    const unsigned short* __restrict__ v_ws, const unsigned short* __restrict__ WoB,
    const float* __restrict__ bo, const float* __restrict__ x, float* __restrict__ out) {
    __shared__ __align__(16) char smem[135168];

    const int tid = threadIdx.x;
    const int lane = tid & 63, wave = tid >> 6;
    const int wj = wave & 3, wi = wave >> 2;
    const int l31 = lane & 31, h = lane >> 5;
    const int b = blockIdx.x & 7;              // batch -> XCD affinity
    const int ibase = (blockIdx.x >> 3) * 128;

    const char* kB = (const char*)(k_ws + (size_t)b * 4096 * 128);  // [j row:256B][swz chunk]
    const char* vB = (const char*)(v_ws + (size_t)b * 128 * 4096);  // [c row:8192B][swz chunk]

    // stage tile kt into buffer buf: linear LDS dest, pre-swizzled global source (chunk ^ row&15)
    auto stage = [&](int buf, int kt) {
        char* Kn = smem + buf * 65536;
        char* Vn = Kn + 32768;
        const size_t kb = (size_t)kt * 32768;  // 128 j * 256 B
        const size_t vb = (size_t)kt * 256;    // 128 j * 2 B
#pragma unroll
        for (int q = 0; q < 4; ++q) {
            int slot = (wave * 4 + q) * 64 + lane;   // 16B slot index 0..2047
            int row = slot >> 4, s = slot & 15;
            int cs = s ^ (row & 15);
            __builtin_amdgcn_global_load_lds(AS1C(kB + kb + (size_t)row * 256 + cs * 16),
                                             AS3(Kn + (wave * 4 + q) * 1024), 16, 0, 0);
            __builtin_amdgcn_global_load_lds(AS1C(vB + vb + (size_t)row * 8192 + cs * 16),
                                             AS3(Vn + (wave * 4 + q) * 1024), 16, 0, 0);
        }
    };

    stage(0, 0);  // prologue: tile 0 -> buffer 0

    // Q fragments: B-operand, col=i (2 iq blocks), k=c
    bf16x8 qf[2][8];
#pragma unroll
    for (int iq = 0; iq < 2; ++iq) {
        const unsigned short* qrow = q_ws + ((size_t)b * 4096 + ibase + wi * 64 + iq * 32 + l31) * 128;
#pragma unroll
        for (int cc = 0; cc < 8; ++cc) qf[iq][cc] = *(const bf16x8*)(qrow + cc * 16 + h * 8);
    }

    f32x16 oac[4][2];
#pragma unroll
    for (int cf = 0; cf < 4; ++cf)
#pragma unroll
        for (int iq = 0; iq < 2; ++iq)
#pragma unroll
            for (int r = 0; r < 16; ++r) oac[cf][iq][r] = 0.f;
    float m0 = -1e30f, m1 = -1e30f, ssum0 = 0.f, ssum1 = 0.f;

    __syncthreads();  // tile 0 staged

#pragma unroll 1
    for (int kt = 0; kt < 32; ++kt) {
        const int cur = kt & 1;
        const char* Kc = smem + cur * 65536;
        const char* Vc = Kc + 32768;
        if (kt < 31) stage(cur ^ 1, kt + 1);  // prefetch (drained at end barrier)

        // S^T[j][i] = K·Q^T over this wave's 32-j slice, both iq blocks
        f32x16 st[2];
#pragma unroll
        for (int iq = 0; iq < 2; ++iq)
#pragma unroll
            for (int r = 0; r < 16; ++r) st[iq][r] = 0.f;
        const int jrow = wj * 32 + l31;
        __builtin_amdgcn_s_setprio(1);
#pragma unroll
        for (int cc = 0; cc < 8; ++cc) {
            unsigned byte = (unsigned)(jrow * 256 + cc * 32 + h * 16) ^ ((jrow & 15) << 4);
            bf16x8 kf = *(const bf16x8*)(Kc + byte);
            st[0] = __builtin_amdgcn_mfma_f32_32x32x16_bf16(kf, qf[0][cc], st[0], 0, 0, 0);
            st[1] = __builtin_amdgcn_mfma_f32_32x32x16_bf16(kf, qf[1][cc], st[1], 0, 0, 0);
        }
        __builtin_amdgcn_s_setprio(0);

        // online softmax per iq over this slice's 32 j (16 in-lane + 1 xor32 shuffle)
        float t0 = st[0][0], t1 = st[1][0];
#pragma unroll
        for (int r = 1; r < 16; ++r) { t0 = fmaxf(t0, st[0][r]); t1 = fmaxf(t1, st[1][r]); }
        t0 = fmaxf(t0, __shfl_xor(t0, 32));
        t1 = fmaxf(t1, __shfl_xor(t1, 32));
        if (!__all(t0 <= m0 && t1 <= m1)) {  // defer-rescale
            float n0 = fmaxf(m0, t0), n1 = fmaxf(m1, t1);
            float c0 = __expf(m0 - n0), c1 = __expf(m1 - n1);
            ssum0 *= c0; ssum1 *= c1;
#pragma unroll
            for (int cf = 0; cf < 4; ++cf)
#pragma unroll
                for (int r = 0; r < 16; ++r) { oac[cf][0][r] *= c0; oac[cf][1][r] *= c1; }
            m0 = n0; m1 = n1;
        }

        // fused exp -> cvt_pk -> permlane32_swap: build PV B-frags pa[js][iq] directly.
        // st[iq][gq*4+r] covers j = 8gq + 4h + r; pa[js][iq] needs j = 16js + 8h + (0..7).
        float ps0 = 0.f, ps1 = 0.f;
        bf16x8 pa[2][2];
#pragma unroll
        for (int js = 0; js < 2; ++js)
#pragma unroll
            for (int iq = 0; iq < 2; ++iq) {
                const float mm = iq ? m1 : m0;
                float pA0 = __expf(st[iq][8 * js + 0] - mm);
                float pA1 = __expf(st[iq][8 * js + 1] - mm);
                float pA2 = __expf(st[iq][8 * js + 2] - mm);
                float pA3 = __expf(st[iq][8 * js + 3] - mm);
                float pB0 = __expf(st[iq][8 * js + 4] - mm);
                float pB1 = __expf(st[iq][8 * js + 5] - mm);
                float pB2 = __expf(st[iq][8 * js + 6] - mm);
                float pB3 = __expf(st[iq][8 * js + 7] - mm);
                float sub = ((pA0 + pA1) + (pA2 + pA3)) + ((pB0 + pB1) + (pB2 + pB3));
                if (iq) ps1 += sub; else ps0 += sub;
                unsigned a0 = cvtpk_bf16(pA0, pA1), a1 = cvtpk_bf16(pA2, pA3);
                unsigned b0 = cvtpk_bf16(pB0, pB1), b1 = cvtpk_bf16(pB2, pB3);
                auto r0 = __builtin_amdgcn_permlane32_swap(a0, b0, false, false);
                auto r1 = __builtin_amdgcn_permlane32_swap(a1, b1, false, false);
                union { unsigned w[4]; bf16x8 v; } pu;
                pu.w[0] = r0[0];
                pu.w[1] = r1[0];
                pu.w[2] = r0[1];
                pu.w[3] = r1[1];
                pa[js][iq] = pu.v;
            }
        ps0 += __shfl_xor(ps0, 32);
        ps1 += __shfl_xor(ps1, 32);
        ssum0 += ps0; ssum1 += ps1;

        // out2[c][i] += V (A, rows c, k=j) x P^T (B, cols i, k=j) over this slice's 32 j
        __builtin_amdgcn_s_setprio(1);
#pragma unroll
        for (int js = 0; js < 2; ++js) {
            const int jcol = wj * 32 + js * 16 + h * 8;
#pragma unroll
            for (int cf = 0; cf < 4; ++cf) {
                int crow = cf * 32 + l31;
                unsigned vbyte = (unsigned)(crow * 256 + jcol * 2) ^ ((crow & 15) << 4);
                bf16x8 va = *(const bf16x8*)(Vc + vbyte);
                oac[cf][0] = __builtin_amdgcn_mfma_f32_32x32x16_bf16(va, pa[js][0], oac[cf][0], 0, 0, 0);
                oac[cf][1] = __builtin_amdgcn_mfma_f32_32x32x16_bf16(va, pa[js][1], oac[cf][1], 0, 0, 0);
            }
        }
        __builtin_amdgcn_s_setprio(0);
        __syncthreads();  // prefetch drained + all reads of cur done -> next iter may restage
    }

    // ---- epilogue: 4-way split-KV combine, then fused 1x1 conv + bias + residual ----
    float* sRed = (float*)(smem + 131072);  // [4 wj][128 i][2] (m, ssum)
    if (h == 0) {
        int it0 = wi * 64 + l31;
        sRed[(wj * 128 + it0) * 2] = m0;
        sRed[(wj * 128 + it0) * 2 + 1] = ssum0;
        sRed[(wj * 128 + it0 + 32) * 2] = m1;
        sRed[(wj * 128 + it0 + 32) * 2 + 1] = ssum1;
    }
    __syncthreads();
    float aS[2];
#pragma unroll
    for (int iq = 0; iq < 2; ++iq) {
        int it = wi * 64 + iq * 32 + l31;
        float ma = sRed[(0 * 128 + it) * 2], sa = sRed[(0 * 128 + it) * 2 + 1];
        float mb = sRed[(1 * 128 + it) * 2], sb = sRed[(1 * 128 + it) * 2 + 1];
        float mc = sRed[(2 * 128 + it) * 2], sc = sRed[(2 * 128 + it) * 2 + 1];
        float md = sRed[(3 * 128 + it) * 2], sd = sRed[(3 * 128 + it) * 2 + 1];
        float M = fmaxf(fmaxf(ma, mb), fmaxf(mc, md));
        float stot = __expf(ma - M) * sa + __expf(mb - M) * sb + __expf(mc - M) * sc + __expf(md - M) * sd;
        float mown = iq ? m1 : m0;
        aS[iq] = __expf(mown - M) / stot;
    }

    // O combine: sBig0 (wj2) / sBig1 (wj3), f32 [128 i][512B row], swz ^((i&7)<<4)
    float* sBig0 = (float*)smem;
    float* sBig1 = (float*)(smem + 65536);
    if (wj >= 2) {
        char* B = (wj == 2) ? (char*)sBig0 : (char*)sBig1;
#pragma unroll
        for (int cf = 0; cf < 4; ++cf)
#pragma unroll
            for (int iq = 0; iq < 2; ++iq)
#pragma unroll
                for (int g = 0; g < 4; ++g) {
                    int it = wi * 64 + iq * 32 + l31;
                    int c = cf * 32 + g * 8 + 4 * h;
                    f32x4 v;
#pragma unroll
                    for (int k = 0; k < 4; ++k) v[k] = oac[cf][iq][4 * g + k] * aS[iq];
                    unsigned byte = (unsigned)(it * 512 + c * 4) ^ ((it & 7) << 4);
                    *(f32x4*)(B + byte) = v;
                }
    }
    __syncthreads();
    if (wj == 0) {  // fold own (scaled) + sBig0 into oac
#pragma unroll
        for (int cf = 0; cf < 4; ++cf)
#pragma unroll
            for (int iq = 0; iq < 2; ++iq)
#pragma unroll
                for (int g = 0; g < 4; ++g) {
                    int it = wi * 64 + iq * 32 + l31;
                    int c = cf * 32 + g * 8 + 4 * h;
                    unsigned byte = (unsigned)(it * 512 + c * 4) ^ ((it & 7) << 4);
                    f32x4 rd = *(const f32x4*)((const char*)sBig0 + byte);
#pragma unroll
                    for (int k = 0; k < 4; ++k) oac[cf][iq][4 * g + k] = oac[cf][iq][4 * g + k] * aS[iq] + rd[k];
                }
    } else if (wj == 1) {  // own (scaled) + sBig1 -> write back sBig1
#pragma unroll
        for (int cf = 0; cf < 4; ++cf)
#pragma unroll
            for (int iq = 0; iq < 2; ++iq)
#pragma unroll
                for (int g = 0; g < 4; ++g) {
                    int it = wi * 64 + iq * 32 + l31;
                    int c = cf * 32 + g * 8 + 4 * h;
                    unsigned byte = (unsigned)(it * 512 + c * 4) ^ ((it & 7) << 4);
                    f32x4 rd = *(const f32x4*)((const char*)sBig1 + byte);
                    f32x4 v;
#pragma unroll
                    for (int k = 0; k < 4; ++k) v[k] = oac[cf][iq][4 * g + k] * aS[iq] + rd[k];
                    *(f32x4*)((char*)sBig1 + byte) = v;
                }
    }
    __syncthreads();
    unsigned short* sOut = (unsigned short*)smem;  // [128 i][128 c] bf16, swz ^((i&15)<<4); aliases sBig0
    if (wj == 0) {
#pragma unroll
        for (int cf = 0; cf < 4; ++cf)
#pragma unroll
            for (int iq = 0; iq < 2; ++iq)
#pragma unroll
                for (int g = 0; g < 4; ++g) {
                    int it = wi * 64 + iq * 32 + l31;
                    int c = cf * 32 + g * 8 + 4 * h;
                    unsigned rbyte = (unsigned)(it * 512 + c * 4) ^ ((it & 7) << 4);
                    f32x4 r1 = *(const f32x4*)((const char*)sBig1 + rbyte);
                    float u0 = oac[cf][iq][4 * g + 0] + r1[0];
                    float u1 = oac[cf][iq][4 * g + 1] + r1[1];
                    float u2 = oac[cf][iq][4 * g + 2] + r1[2];
                    float u3 = oac[cf][iq][4 * g + 3] + r1[3];
                    uint2 pk;
                    pk.x = cvtpk_bf16(u0, u1);
                    pk.y = cvtpk_bf16(u2, u3);
                    unsigned wbyte = (unsigned)(it * 256 + c * 2) ^ ((it & 15) << 4);
                    *(uint2*)((char*)sOut + wbyte) = pk;
                }
    }
    __syncthreads();

    // 1x1 conv: D[o][i] = Wo x out2, 16 tiles of 32x32 over 8 waves (2 each)
#pragma unroll
    for (int t = 0; t < 2; ++t) {
        int tt = wave + t * 8;
        int of = tt >> 2, ifl = tt & 3;
        int ir = ifl * 32 + l31;
        f32x16 acc;
#pragma unroll
        for (int r = 0; r < 16; ++r) acc[r] = 0.f;
#pragma unroll
        for (int cc = 0; cc < 8; ++cc) {
            unsigned bbyte = (unsigned)(ir * 256 + cc * 32 + h * 16) ^ ((ir & 15) << 4);
            bf16x8 bfr = *(const bf16x8*)((const char*)sOut + bbyte);
            bf16x8 wa = *(const bf16x8*)(WoB + (of * 32 + l31) * 128 + cc * 16 + h * 8);
            acc = __builtin_amdgcn_mfma_f32_32x32x16_bf16(wa, bfr, acc, 0, 0, 0);
        }
        int iglob = ibase + ir;
#pragma unroll
        for (int r = 0; r < 16; ++r) {
            int o = of * 32 + (r & 3) + 8 * (r >> 2) + 4 * h;
            size_t gidx = ((size_t)b * 128 + o) * 4096 + iglob;
            out[gidx] = acc[r] + bo[o] + x[gidx];
        }
    }
}

extern "C" void kernel_launch(void* const* d_in, const int* in_sizes, int n_in,
                              void* d_out, int out_size, void* d_ws, size_t ws_size,
                              hipStream_t stream) {
    const float* x  = (const float*)d_in[0];
    const float* Wq = (const float*)d_in[1];
    const float* bq = (const float*)d_in[2];
    const float* Wk = (const float*)d_in[3];
    const float* bk = (const float*)d_in[4];
    const float* Wv = (const float*)d_in[5];
    const float* bv = (const float*)d_in[6];
    const float* Wo = (const float*)d_in[7];
    const float* bo = (const float*)d_in[8];
    char* ws = (char*)d_ws;
    unsigned short* q_ws = (unsigned short*)(ws);              //  8 MB  [b][n][c] bf16 (pre-scaled)
    unsigned short* k_ws = (unsigned short*)(ws + 8388608);    //  8 MB  [b][n][c] bf16
    unsigned short* v_ws = (unsigned short*)(ws + 16777216);   //  8 MB  [b][c][n] bf16
    unsigned short* RW   = (unsigned short*)(ws + 25165824);   //  884 KB repacked qkv weights
    unsigned short* WoB  = (unsigned short*)(ws + 26050560);   //  32 KB  Wo bf16
    float* out = (float*)d_out;

    hipLaunchKernelGGL(repack_k, dim3(1792), dim3(256), 0, stream, Wq, Wk, Wv, Wo, RW, WoB);
    hipLaunchKernelGGL(qkv_conv_k, dim3(512), dim3(256), 0, stream, x, RW, bq, bk, bv, q_ws, k_ws, v_ws);
    hipLaunchKernelGGL(attn_k, dim3(256), dim3(512), 0, stream, q_ws, k_ws, v_ws, WoB, bo, x, out);
}

// Round 6
// 162.812 us; speedup vs baseline: 1.7197x; 1.6107x over previous
//
#include <hip/hip_runtime.h>

typedef __attribute__((ext_vector_type(8))) short bf16x8;
typedef __attribute__((ext_vector_type(4))) float f32x4;
typedef __attribute__((ext_vector_type(16))) float f32x16;

static __device__ __forceinline__ unsigned short f2bf(float f) {
    union { float f; unsigned int u; } v; v.f = f;
    unsigned int r = v.u + 0x7FFFu + ((v.u >> 16) & 1u);
    return (unsigned short)(r >> 16);
}

static __device__ __forceinline__ unsigned cvtpk_bf16(float lo, float hi) {
    unsigned r;
    asm("v_cvt_pk_bf16_f32 %0, %1, %2" : "=v"(r) : "v"(lo), "v"(hi));
    return r;
}

#define NRW (27 * 16384)

// Repack Wq/Wk/Wv -> RW[conv][kh][kw][cc][g][o][8s] bf16 (B-frag-ready), Wo -> bf16 [o][c]
__global__ __launch_bounds__(256) void repack_k(const float* __restrict__ Wq, const float* __restrict__ Wk,
                                                const float* __restrict__ Wv, const float* __restrict__ Wo,
                                                unsigned short* __restrict__ RW, unsigned short* __restrict__ WoB) {
    int t = blockIdx.x * 256 + threadIdx.x;
    if (t < NRW) {
        int s = t & 7, o = (t >> 3) & 127, g = (t >> 10) & 3, cc = (t >> 12) & 3, tap = t >> 14;
        int conv = tap / 9, kk = tap % 9, kh = kk / 3, kw = kk % 3;
        int c = cc * 32 + g * 8 + s;
        const float* W = (conv == 0) ? Wq : ((conv == 1) ? Wk : Wv);
        RW[t] = f2bf(W[((o * 128 + c) * 3 + kh) * 3 + kw]);
    } else {
        int u = t - NRW;
        if (u < 16384) WoB[u] = f2bf(Wo[u]);
    }
}

// Fused QKV 3x3 conv, implicit GEMM. Block = (b, h): M=64 (w), N=384 (3 convs x 128 o), K=1152.
__global__ __launch_bounds__(256) void qkv_conv_k(const float* __restrict__ x, const unsigned short* __restrict__ RW,
                                                  const float* __restrict__ bq, const float* __restrict__ bk,
                                                  const float* __restrict__ bv,
                                                  unsigned short* __restrict__ q_ws, unsigned short* __restrict__ k_ws,
                                                  unsigned short* __restrict__ v_ws) {
    __shared__ unsigned short xs[3 * 66 * 128];  // [kh][w+1 (66 padded)][c], swizzled ^((row&7)<<4)
    const int tid = threadIdx.x;
    const int b = blockIdx.x >> 6, h = blockIdx.x & 63;
    for (int i = tid; i < 3 * 66 * 128; i += 256) xs[i] = 0;
    __syncthreads();
    for (int ch = tid; ch < 3 * 128 * 16; ch += 256) {
        int r3 = ch >> 11, rem = ch & 2047, c = rem >> 4, w4 = rem & 15;
        int hh = h - 1 + r3;
        if (hh >= 0 && hh < 64) {
            float4 v = *(const float4*)(x + ((b * 128 + c) * 64 + hh) * 64 + w4 * 4);
            float vv[4] = {v.x, v.y, v.z, v.w};
#pragma unroll
            for (int j = 0; j < 4; ++j) {
                int wr = w4 * 4 + j + 1;
                unsigned int byte = (unsigned int)(((r3 * 66 + wr) * 128 + c) * 2) ^ ((wr & 7) << 4);
                *(unsigned short*)((char*)xs + byte) = f2bf(vv[j]);
            }
        }
    }
    __syncthreads();
    const int lane = tid & 63, wave = tid >> 6;
    const int l15 = lane & 15, g = lane >> 4;
    f32x4 acc[4][6];
#pragma unroll
    for (int i = 0; i < 4; ++i)
#pragma unroll
        for (int j = 0; j < 6; ++j) acc[i][j] = (f32x4){0.f, 0.f, 0.f, 0.f};
#pragma unroll 1
    for (int kk = 0; kk < 9; ++kk) {
        const int kw = kk % 3;
#pragma unroll 2
        for (int cc = 0; cc < 4; ++cc) {
            bf16x8 a[4];
#pragma unroll
            for (int mf = 0; mf < 4; ++mf) {
                int wr = mf * 16 + l15 + kw;
                unsigned int byte = (unsigned int)((((kk / 3) * 66 + wr) * 128 + cc * 32 + g * 8) * 2) ^ ((wr & 7) << 4);
                a[mf] = *(const bf16x8*)((const char*)xs + byte);
            }
#pragma unroll
            for (int n6 = 0; n6 < 6; ++n6) {
                int nt = wave * 6 + n6;
                int conv = nt >> 3;
                int o = (nt * 16 + l15) & 127;
                bf16x8 bfr = *(const bf16x8*)(RW + ((((conv * 9 + kk) * 4 + cc) * 4 + g) * 128 + o) * 8);
#pragma unroll
                for (int mf = 0; mf < 4; ++mf)
                    acc[mf][n6] = __builtin_amdgcn_mfma_f32_16x16x32_bf16(a[mf], bfr, acc[mf][n6], 0, 0, 0);
            }
        }
    }
    const float SCALE = 0.08838834764831845f;  // 1/sqrt(128), folded into q
#pragma unroll
    for (int n6 = 0; n6 < 6; ++n6) {
        int nt = wave * 6 + n6;
        int conv = nt >> 3;
        int o = (nt * 16 + l15) & 127;
        float bias = (conv == 0) ? bq[o] : ((conv == 1) ? bk[o] : bv[o]);
#pragma unroll
        for (int mf = 0; mf < 4; ++mf) {
#pragma unroll
            for (int r = 0; r < 4; ++r) {
                int pos = h * 64 + mf * 16 + g * 4 + r;
                float val = acc[mf][n6][r] + bias;
                if (conv == 0)      q_ws[(b * 4096 + pos) * 128 + o] = f2bf(val * SCALE);
                else if (conv == 1) k_ws[(b * 4096 + pos) * 128 + o] = f2bf(val);
                else                v_ws[(b * 128 + o) * 4096 + pos] = f2bf(val);
            }
        }
    }
}

#define AS1C(p) ((const __attribute__((address_space(1))) void*)(p))
#define AS3(p)  ((__attribute__((address_space(3))) void*)(p))

// Flash attention + fused 1x1 conv + bias + residual.
// Block = (b, 64-row q tile), 4 waves = 2 wi (32 i) x 2 wj (32 j). KV tile = 64 j,
// double-buffered (2x32KB); 66KB LDS -> 2 blocks/CU (2 waves/SIMD from DIFFERENT
// blocks = barrier-decoupled TLP). Per-wave regs ~150 << 256 cap: no spill by design.
// P exchange fully in-register via cvt_pk + permlane32_swap (r3/r5-verified path).
__global__ __launch_bounds__(256, 2) void attn_k(
    const unsigned short* __restrict__ q_ws, const unsigned short* __restrict__ k_ws,
    const unsigned short* __restrict__ v_ws, const unsigned short* __restrict__ WoB,
    const float* __restrict__ bo, const float* __restrict__ x, float* __restrict__ out) {
    __shared__ __align__(16) char smem[66560];

    const int tid = threadIdx.x;
    const int lane = tid & 63, wave = tid >> 6;
    const int wj = wave & 1, wi = wave >> 1;
    const int l31 = lane & 31, h = lane >> 5;
    const int b = blockIdx.x & 7;              // batch -> XCD affinity (K/V in one XCD L2)
    const int qt = blockIdx.x >> 3;            // 0..63
    const int ibase = qt * 64;

    const char* kB = (const char*)(k_ws + (size_t)b * 4096 * 128);  // [j][c], 256B rows
    const char* vB = (const char*)(v_ws + (size_t)b * 128 * 4096);  // [c][j], 8192B rows

    // stage 64j tile kt into buffer buf: linear LDS dest, pre-swizzled global source.
    // K sub-tile: 64 rows x 16 chunks (swz ^row&15); V sub-tile: 128 rows x 8 chunks (swz ^row&7).
    auto stage = [&](int buf, int kt) {
        char* Kn = smem + buf * 32768;
        char* Vn = Kn + 16384;
#pragma unroll
        for (int q = 0; q < 4; ++q) {
            int slot = (wave * 4 + q) * 64 + lane;  // 0..1023
            int krow = slot >> 4, ks = slot & 15;
            int kcs = ks ^ (krow & 15);
            __builtin_amdgcn_global_load_lds(AS1C(kB + (size_t)(kt * 64 + krow) * 256 + kcs * 16),
                                             AS3(Kn + slot * 16), 16, 0, 0);
            int vrow = slot >> 3, vs = slot & 7;
            int vcs = vs ^ (vrow & 7);
            __builtin_amdgcn_global_load_lds(AS1C(vB + (size_t)vrow * 8192 + kt * 128 + vcs * 16),
                                             AS3(Vn + slot * 16), 16, 0, 0);
        }
    };

    stage(0, 0);  // prologue: tile 0 -> buffer 0

    // Q fragments: B-operand, col = i = wi*32 + l31, k=c
    bf16x8 qf[8];
    {
        const unsigned short* qrow = q_ws + ((size_t)b * 4096 + ibase + wi * 32 + l31) * 128;
#pragma unroll
        for (int cc = 0; cc < 8; ++cc) qf[cc] = *(const bf16x8*)(qrow + cc * 16 + h * 8);
    }

    f32x16 oac[4];
#pragma unroll
    for (int cf = 0; cf < 4; ++cf)
#pragma unroll
        for (int r = 0; r < 16; ++r) oac[cf][r] = 0.f;
    float m = -1e30f, ssum = 0.f;

    __syncthreads();  // tile 0 staged

#pragma unroll 1
    for (int kt = 0; kt < 64; ++kt) {
        const int cur = kt & 1;
        const char* Kc = smem + cur * 32768;
        const char* Vc = Kc + 16384;
        if (kt < 63) stage(cur ^ 1, kt + 1);  // prefetch (drained at end barrier)

        // S^T[j][i] = K·Q^T over this wave's 32-j slice
        f32x16 st;
#pragma unroll
        for (int r = 0; r < 16; ++r) st[r] = 0.f;
        const int jrow = wj * 32 + l31;
        __builtin_amdgcn_s_setprio(1);
#pragma unroll
        for (int cc = 0; cc < 8; ++cc) {
            unsigned byte = (unsigned)(jrow * 256 + (((cc * 2 + h) ^ (jrow & 15)) << 4));
            bf16x8 kf = *(const bf16x8*)(Kc + byte);
            st = __builtin_amdgcn_mfma_f32_32x32x16_bf16(kf, qf[cc], st, 0, 0, 0);
        }
        __builtin_amdgcn_s_setprio(0);

        // online softmax over this slice's 32 j (16 in-lane + 1 xor32 shuffle)
        float tmax = st[0];
#pragma unroll
        for (int r = 1; r < 16; ++r) tmax = fmaxf(tmax, st[r]);
        tmax = fmaxf(tmax, __shfl_xor(tmax, 32));
        if (!__all(tmax <= m)) {  // defer-rescale
            float mnew = fmaxf(m, tmax);
            float corr = __expf(m - mnew);
            ssum *= corr;
#pragma unroll
            for (int cf = 0; cf < 4; ++cf)
#pragma unroll
                for (int r = 0; r < 16; ++r) oac[cf][r] *= corr;
            m = mnew;
        }

        // fused exp -> cvt_pk -> permlane32_swap: PV B-frags pa[js]
        // st[gq*4+r] holds j = 8gq + 4h + r; pa[js] needs j = 16js + 8h + (0..7).
        float ps = 0.f;
        bf16x8 pa[2];
#pragma unroll
        for (int js = 0; js < 2; ++js) {
            float pA0 = __expf(st[8 * js + 0] - m);
            float pA1 = __expf(st[8 * js + 1] - m);
            float pA2 = __expf(st[8 * js + 2] - m);
            float pA3 = __expf(st[8 * js + 3] - m);
            float pB0 = __expf(st[8 * js + 4] - m);
            float pB1 = __expf(st[8 * js + 5] - m);
            float pB2 = __expf(st[8 * js + 6] - m);
            float pB3 = __expf(st[8 * js + 7] - m);
            ps += ((pA0 + pA1) + (pA2 + pA3)) + ((pB0 + pB1) + (pB2 + pB3));
            unsigned a0 = cvtpk_bf16(pA0, pA1), a1 = cvtpk_bf16(pA2, pA3);
            unsigned b0 = cvtpk_bf16(pB0, pB1), b1 = cvtpk_bf16(pB2, pB3);
            auto r0 = __builtin_amdgcn_permlane32_swap(a0, b0, false, false);
            auto r1 = __builtin_amdgcn_permlane32_swap(a1, b1, false, false);
            union { unsigned w[4]; bf16x8 v; } pu;
            pu.w[0] = r0[0];
            pu.w[1] = r1[0];
            pu.w[2] = r0[1];
            pu.w[3] = r1[1];
            pa[js] = pu.v;
        }
        ps += __shfl_xor(ps, 32);
        ssum += ps;

        // out2[c][i] += V (A, rows c, k=j) x P^T (B, cols i, k=j) over this slice's 32 j
        __builtin_amdgcn_s_setprio(1);
#pragma unroll
        for (int js = 0; js < 2; ++js) {
            const int chunk = wj * 4 + js * 2 + h;  // jcol/8, jcol = wj*32+js*16+h*8
#pragma unroll
            for (int cf = 0; cf < 4; ++cf) {
                int crow = cf * 32 + l31;
                unsigned vbyte = (unsigned)(crow * 128 + ((chunk ^ (crow & 7)) << 4));
                bf16x8 va = *(const bf16x8*)(Vc + vbyte);
                oac[cf] = __builtin_amdgcn_mfma_f32_32x32x16_bf16(va, pa[js], oac[cf], 0, 0, 0);
            }
        }
        __builtin_amdgcn_s_setprio(0);
        __syncthreads();  // prefetch drained + all reads of cur done -> next iter may restage
    }

    // ---- epilogue: 2-way split-KV combine, then fused 1x1 conv + bias + residual ----
    float* sRed = (float*)(smem + 65536);  // [2 wj][64 i][2] (m, ssum)
    const int it = wi * 32 + l31;
    if (h == 0) {
        sRed[(wj * 64 + it) * 2] = m;
        sRed[(wj * 64 + it) * 2 + 1] = ssum;
    }
    __syncthreads();
    float m1 = sRed[((wj ^ 1) * 64 + it) * 2];
    float s1 = sRed[((wj ^ 1) * 64 + it) * 2 + 1];
    float M = fmaxf(m, m1);
    float aS = __expf(m - M);
    float inv = 1.0f / (aS * ssum + __expf(m1 - M) * s1);

    char* sBig = smem + 32768;  // f32 [64 i][128 c] swz ^((i&7)<<4), 32KB over buf1
    if (wj == 1) {
#pragma unroll
        for (int cf = 0; cf < 4; ++cf)
#pragma unroll
            for (int g = 0; g < 4; ++g) {
                int c = cf * 32 + g * 8 + 4 * h;
                f32x4 v4;
#pragma unroll
                for (int k = 0; k < 4; ++k) v4[k] = aS * oac[cf][4 * g + k];
                unsigned byte = (unsigned)(it * 512 + c * 4) ^ ((it & 7) << 4);
                *(f32x4*)(sBig + byte) = v4;
            }
    }
    __syncthreads();
    unsigned short* sOut = (unsigned short*)smem;  // bf16 [64 i][128 c] swz ^((i&15)<<4), 16KB
    if (wj == 0) {
#pragma unroll
        for (int cf = 0; cf < 4; ++cf)
#pragma unroll
            for (int g = 0; g < 4; ++g) {
                int c = cf * 32 + g * 8 + 4 * h;
                unsigned rbyte = (unsigned)(it * 512 + c * 4) ^ ((it & 7) << 4);
                f32x4 rd = *(const f32x4*)((const char*)sBig + rbyte);
                float u0 = (aS * oac[cf][4 * g + 0] + rd[0]) * inv;
                float u1 = (aS * oac[cf][4 * g + 1] + rd[1]) * inv;
                float u2 = (aS * oac[cf][4 * g + 2] + rd[2]) * inv;
                float u3 = (aS * oac[cf][4 * g + 3] + rd[3]) * inv;
                uint2 pk;
                pk.x = cvtpk_bf16(u0, u1);
                pk.y = cvtpk_bf16(u2, u3);
                unsigned wbyte = (unsigned)(it * 256 + c * 2) ^ ((it & 15) << 4);
                *(uint2*)((char*)sOut + wbyte) = pk;
            }
    }
    __syncthreads();

    // 1x1 conv: D[o][i] = Wo x out2, 8 tiles of 32x32 (4 of x 2 ifl) over 4 waves (2 each)
#pragma unroll
    for (int t = 0; t < 2; ++t) {
        int tt = wave * 2 + t;
        int of = tt >> 1, ifl = tt & 1;
        int ir = ifl * 32 + l31;
        f32x16 acc;
#pragma unroll
        for (int r = 0; r < 16; ++r) acc[r] = 0.f;
#pragma unroll
        for (int cc = 0; cc < 8; ++cc) {
            unsigned bbyte = (unsigned)(ir * 256 + cc * 32 + h * 16) ^ ((ir & 15) << 4);
            bf16x8 bfr = *(const bf16x8*)((const char*)sOut + bbyte);
            bf16x8 wa = *(const bf16x8*)(WoB + (of * 32 + l31) * 128 + cc * 16 + h * 8);
            acc = __builtin_amdgcn_mfma_f32_32x32x16_bf16(wa, bfr, acc, 0, 0, 0);
        }
        int iglob = ibase + ir;
#pragma unroll
        for (int r = 0; r < 16; ++r) {
            int o = of * 32 + (r & 3) + 8 * (r >> 2) + 4 * h;
            size_t gidx = ((size_t)b * 128 + o) * 4096 + iglob;
            out[gidx] = acc[r] + bo[o] + x[gidx];
        }
    }
}

extern "C" void kernel_launch(void* const* d_in, const int* in_sizes, int n_in,
                              void* d_out, int out_size, void* d_ws, size_t ws_size,
                              hipStream_t stream) {
    const float* x  = (const float*)d_in[0];
    const float* Wq = (const float*)d_in[1];
    const float* bq = (const float*)d_in[2];
    const float* Wk = (const float*)d_in[3];
    const float* bk = (const float*)d_in[4];
    const float* Wv = (const float*)d_in[5];
    const float* bv = (const float*)d_in[6];
    const float* Wo = (const float*)d_in[7];
    const float* bo = (const float*)d_in[8];
    char* ws = (char*)d_ws;
    unsigned short* q_ws = (unsigned short*)(ws);              //  8 MB  [b][n][c] bf16 (pre-scaled)
    unsigned short* k_ws = (unsigned short*)(ws + 8388608);    //  8 MB  [b][n][c] bf16
    unsigned short* v_ws = (unsigned short*)(ws + 16777216);   //  8 MB  [b][c][n] bf16
    unsigned short* RW   = (unsigned short*)(ws + 25165824);   //  884 KB repacked qkv weights
    unsigned short* WoB  = (unsigned short*)(ws + 26050560);   //  32 KB  Wo bf16
    float* out = (float*)d_out;

    hipLaunchKernelGGL(repack_k, dim3(1792), dim3(256), 0, stream, Wq, Wk, Wv, Wo, RW, WoB);
    hipLaunchKernelGGL(qkv_conv_k, dim3(512), dim3(256), 0, stream, x, RW, bq, bk, bv, q_ws, k_ws, v_ws);
    hipLaunchKernelGGL(attn_k, dim3(512), dim3(256), 0, stream, q_ws, k_ws, v_ws, WoB, bo, x, out);
}